// Round 1
// baseline (99.843 us; speedup 1.0000x reference)
//
#include <hip/hip_runtime.h>
#include <hip/hip_fp16.h>

#define IN_DIM 32768
#define BATCH 2048
#define CLASSES 10
#define NC 4                                 // column chunks (cross-block K split)
#define RB 8                                 // rows per block/thread
#define TPB 256
#define COLS_PER_CHUNK (IN_DIM / NC)         // 8192
#define JITER (COLS_PER_CHUNK / TPB)         // 32
#define TAB_HALVES 24                        // 20 used + 4 pad -> 48 B/col, 16B-aligned
#define OUT_SCALE 0.005524271728019903f      // 1/sqrt(32768)

// ---------------- stage 0: weight trig table ----------------
// tab[c*24 + 2o] = cos(2*pi*round(w[o][c])/8), tab[c*24+2o+1] = sin(...)
__global__ __launch_bounds__(256) void build_table(const float* __restrict__ w,
                                                   __half* __restrict__ tab) {
    int c = blockIdx.x * blockDim.x + threadIdx.x;
    if (c >= IN_DIM) return;
    __half2* t2 = (__half2*)(tab + (size_t)c * TAB_HALVES);
#pragma unroll
    for (int o = 0; o < CLASSES; ++o) {
        float wv = w[(size_t)o * IN_DIM + c];
        float k = rintf(wv);                 // round-half-even, matches jnp.round
        float rev = k * 0.125f;              // theta*k / (2*pi) = k/8 revolutions
        float ck = __builtin_amdgcn_cosf(rev);
        float sk = __builtin_amdgcn_sinf(rev);
        t2[o] = __floats2half2_rn(ck, sk);
    }
    t2[10] = __floats2half2_rn(0.f, 0.f);    // pad
    t2[11] = __floats2half2_rn(0.f, 0.f);
}

// ---------------- stage 1: main streaming kernel ----------------
// grid = (BATCH/RB) * NC blocks; each block: 8 rows x 8192 cols.
// Each thread: 8 rows x 32 cols (strided by 256), acc[8][10] in VGPRs.
__global__ __launch_bounds__(256, 3) void gsim_main(const float* __restrict__ x,
                                                    const __half* __restrict__ tab,
                                                    float* __restrict__ part) {
    __shared__ float lds[128][84];           // 43 KB reduction scratch
    const int chunk = blockIdx.x % NC;
    const int rowblk = blockIdx.x / NC;
    const int tid = threadIdx.x;
    const int row0 = rowblk * RB;
    const int cbase = chunk * COLS_PER_CHUNK;

    float acc[RB][CLASSES];
#pragma unroll
    for (int r = 0; r < RB; ++r)
#pragma unroll
        for (int o = 0; o < CLASSES; ++o) acc[r][o] = 0.f;

    const float* xbase = x + (size_t)row0 * IN_DIM + cbase + tid;

    for (int j = 0; j < JITER; ++j) {
        const int c = cbase + j * TPB + tid;
        // 48 B table load (3x dwordx4), L2-resident
        const uint4* tp = (const uint4*)(tab + (size_t)c * TAB_HALVES);
        uint4 t0 = tp[0];
        uint4 t1 = tp[1];
        uint4 t2v = tp[2];
        unsigned int wd[10] = {t0.x, t0.y, t0.z, t0.w,
                               t1.x, t1.y, t1.z, t1.w,
                               t2v.x, t2v.y};
        float ck[CLASSES], sk[CLASSES];
#pragma unroll
        for (int o = 0; o < CLASSES; ++o) {
            __half2 h = *(__half2*)&wd[o];
            float2 f = __half22float2(h);
            ck[o] = f.x;
            sk[o] = f.y;
        }

        const float* xp = xbase + (size_t)j * TPB;
#pragma unroll
        for (int r = 0; r < RB; ++r) {
            float xv = __builtin_nontemporal_load(xp + (size_t)r * IN_DIM);
            float rev = xv * 0.125f;         // theta*x/(2*pi)
            float cx = __builtin_amdgcn_cosf(rev);
            float sx = __builtin_amdgcn_sinf(rev);
#pragma unroll
            for (int o = 0; o < CLASSES; ++o)
                acc[r][o] = fmaf(cx, ck[o], fmaf(sx, sk[o], acc[r][o]));
        }
    }

    // ---- block reduction: 256 threads -> 80 partial sums ----
    // round 1: 256 -> 128
    if (tid >= 128) {
#pragma unroll
        for (int r = 0; r < RB; ++r)
#pragma unroll
            for (int o = 0; o < CLASSES; ++o)
                lds[tid - 128][r * CLASSES + o] = acc[r][o];
    }
    __syncthreads();
    if (tid < 128) {
#pragma unroll
        for (int r = 0; r < RB; ++r)
#pragma unroll
            for (int o = 0; o < CLASSES; ++o) {
                acc[r][o] += lds[tid][r * CLASSES + o];
                lds[tid][r * CLASSES + o] = acc[r][o];
            }
    }
    __syncthreads();
    // 80 collectors: value v = r*10+o summed over 128 threads (fixed order)
    if (tid < RB * CLASSES) {
        float s = 0.f;
        for (int t = 0; t < 128; ++t) s += lds[t][tid];
        // part[chunk][row0 + tid/10][tid%10] -> contiguous 80 floats
        part[(size_t)chunk * (BATCH * CLASSES) + (size_t)row0 * CLASSES + tid] = s;
    }
}

// ---------------- stage 2: fold NC partials + scale ----------------
__global__ __launch_bounds__(256) void reduce_out(const float* __restrict__ part,
                                                  const float* __restrict__ radius,
                                                  float* __restrict__ out) {
    int i = blockIdx.x * blockDim.x + threadIdx.x;
    if (i >= BATCH * CLASSES) return;
    float s = 0.f;
#pragma unroll
    for (int c = 0; c < NC; ++c) s += part[(size_t)c * (BATCH * CLASSES) + i];
    out[i] = s * radius[0] * OUT_SCALE;
}

extern "C" void kernel_launch(void* const* d_in, const int* in_sizes, int n_in,
                              void* d_out, int out_size, void* d_ws, size_t ws_size,
                              hipStream_t stream) {
    const float* x = (const float*)d_in[0];
    const float* w = (const float*)d_in[1];
    const float* radius = (const float*)d_in[2];
    float* out = (float*)d_out;

    __half* tab = (__half*)d_ws;                                  // 1.57 MB
    float* part = (float*)((char*)d_ws + (size_t)IN_DIM * TAB_HALVES * sizeof(__half));
    // part: NC * 2048 * 10 f32 = 320 KB; total ws use ~1.9 MB

    build_table<<<IN_DIM / 256, 256, 0, stream>>>(w, tab);
    gsim_main<<<(BATCH / RB) * NC, 256, 0, stream>>>(x, tab, part);
    reduce_out<<<(BATCH * CLASSES + 255) / 256, 256, 0, stream>>>(part, radius, out);
}